// Round 1
// baseline (131.223 us; speedup 1.0000x reference)
//
#include <hip/hip_runtime.h>

// Problem constants
#define B_  16
#define T_  256
#define K_  128
#define DE_ 256
#define DK_ 256
#define U_  128
#define TT_ 8      // timesteps per block in the fused kernel

// Static device scratch (avoids dependence on ws_size).
// E2[m][u]  = 2*(enc@W1 + b1), m in [0, B*T)
// Km2[n][u] = 2*(knw@W2 + b2), n in [0, B*K)
__device__ float g_E2[B_ * T_ * U_];
__device__ float g_Km2[B_ * K_ * U_];

// ---------------------------------------------------------------------------
// Generic GEMM: Y[m][u] = 2*(sum_d X[m][d]*W[d][u] + bias[u]), D=256, U=128.
// One block = 8 rows x 128 u. sel: 0 -> g_E2, 1 -> g_Km2.
// ---------------------------------------------------------------------------
__global__ __launch_bounds__(256) void gemm2x(const float* __restrict__ X,
                                              const float* __restrict__ W,
                                              const float* __restrict__ bias,
                                              int sel) {
    __shared__ float Xs[8][256];
    float* __restrict__ Y = sel ? g_Km2 : g_E2;

    const int tid  = threadIdx.x;
    const int row0 = blockIdx.x * 8;

    // Stage 8 rows of X (8*256 floats = 512 float4), coalesced.
    for (int i = tid; i < 512; i += 256) {
        const int rr = i >> 6, cc = i & 63;
        *(float4*)&Xs[rr][cc * 4] =
            *(const float4*)&X[(row0 + rr) * 256 + cc * 4];
    }
    __syncthreads();

    const int r  = tid >> 5;        // 0..7  (row within tile)
    const int uc = tid & 31;        // 0..31 (u4 = 4*uc)
    float4 acc = {0.f, 0.f, 0.f, 0.f};

    for (int d = 0; d < 256; d += 4) {
        const float4 x4 = *(const float4*)&Xs[r][d];   // broadcast LDS read
        const float* wp = &W[d * 128 + uc * 4];
        const float4 w0 = *(const float4*)(wp);
        const float4 w1 = *(const float4*)(wp + 128);
        const float4 w2 = *(const float4*)(wp + 256);
        const float4 w3 = *(const float4*)(wp + 384);
        acc.x = fmaf(x4.x, w0.x, acc.x); acc.y = fmaf(x4.x, w0.y, acc.y);
        acc.z = fmaf(x4.x, w0.z, acc.z); acc.w = fmaf(x4.x, w0.w, acc.w);
        acc.x = fmaf(x4.y, w1.x, acc.x); acc.y = fmaf(x4.y, w1.y, acc.y);
        acc.z = fmaf(x4.y, w1.z, acc.z); acc.w = fmaf(x4.y, w1.w, acc.w);
        acc.x = fmaf(x4.z, w2.x, acc.x); acc.y = fmaf(x4.z, w2.y, acc.y);
        acc.z = fmaf(x4.z, w2.z, acc.z); acc.w = fmaf(x4.z, w2.w, acc.w);
        acc.x = fmaf(x4.w, w3.x, acc.x); acc.y = fmaf(x4.w, w3.y, acc.y);
        acc.z = fmaf(x4.w, w3.z, acc.z); acc.w = fmaf(x4.w, w3.w, acc.w);
    }

    const float4 b4 = *(const float4*)&bias[uc * 4];
    float4 o;
    o.x = 2.f * (acc.x + b4.x);
    o.y = 2.f * (acc.y + b4.y);
    o.z = 2.f * (acc.z + b4.z);
    o.w = 2.f * (acc.w + b4.w);
    *(float4*)&Y[(row0 + r) * 128 + uc * 4] = o;
}

// ---------------------------------------------------------------------------
// Fused scores -> softmax -> context. One block per (b, tile of 8 t's).
// tanh(x) = 1 - 2/(1 + e^{2x}); E2/Km2 already hold 2*(.). Constant terms
// (sum_u V[u], bV) cancel in softmax over K and are dropped.
// ---------------------------------------------------------------------------
__global__ __launch_bounds__(256) void attn_ctx(const float* __restrict__ knw,
                                                const float* __restrict__ V,
                                                float* __restrict__ out) {
    __shared__ float E2s[TT_][U_];       // 4 KB
    __shared__ float V2s[U_];            // 0.5 KB
    __shared__ float attn[TT_][K_];      // 4 KB
    __shared__ float part[2 * K_];       // 1 KB
    __shared__ float part2[4][TT_][DK_]; // 32 KB

    const int tid  = threadIdx.x;
    const int blk  = blockIdx.x;
    const int b    = blk >> 5;           // 32 t-tiles per batch
    const int t0   = (blk & 31) * TT_;
    const int lane = tid & 63;
    const int wave = tid >> 6;

    // Stage 2*V
    if (tid < U_) V2s[tid] = 2.0f * V[tid];
    // Stage E2 rows for this t-tile (8*128 floats, one float4/thread)
    {
        const int ti = tid >> 5, uc = tid & 31;
        *(float4*)&E2s[ti][uc * 4] =
            *(const float4*)&g_E2[(b * T_ + t0 + ti) * U_ + uc * 4];
    }

    // Each thread owns (k, half-of-U): Km row half lives in 64 VGPRs,
    // reused across all 8 timesteps.
    const int k_idx = tid & 127;
    const int half  = tid >> 7;
    float4 km[16];
    {
        const float* kp = &g_Km2[(b * K_ + k_idx) * U_ + half * 64];
#pragma unroll
        for (int c = 0; c < 16; c++) km[c] = *(const float4*)&kp[c * 4];
    }
    __syncthreads();

    // ---- Phase 1: scores + softmax per timestep ----
    for (int t = 0; t < TT_; t++) {
        float negacc = 0.f;   // sum_u 2V[u] / (1 + e^{2(e+k)}) over this half
#pragma unroll
        for (int c = 0; c < 16; c++) {
            const float4 e4 = *(const float4*)&E2s[t][half * 64 + c * 4];
            const float4 v4 = *(const float4*)&V2s[half * 64 + c * 4];
            float x, r;
            x = e4.x + km[c].x; r = __builtin_amdgcn_rcpf(1.0f + __expf(x));
            negacc = fmaf(v4.x, r, negacc);
            x = e4.y + km[c].y; r = __builtin_amdgcn_rcpf(1.0f + __expf(x));
            negacc = fmaf(v4.y, r, negacc);
            x = e4.z + km[c].z; r = __builtin_amdgcn_rcpf(1.0f + __expf(x));
            negacc = fmaf(v4.z, r, negacc);
            x = e4.w + km[c].w; r = __builtin_amdgcn_rcpf(1.0f + __expf(x));
            negacc = fmaf(v4.w, r, negacc);
        }
        part[tid] = negacc;              // layout [half][k] == [tid]
        __syncthreads();

        if (wave == 0) {                 // softmax over K=128 by wave 0
            float s0 = -(part[lane] + part[128 + lane]);
            float s1 = -(part[64 + lane] + part[192 + lane]);
            float m = fmaxf(s0, s1);
#pragma unroll
            for (int off = 32; off >= 1; off >>= 1)
                m = fmaxf(m, __shfl_xor(m, off));
            float e0 = __expf(s0 - m), e1 = __expf(s1 - m);
            float ss = e0 + e1;
#pragma unroll
            for (int off = 32; off >= 1; off >>= 1)
                ss += __shfl_xor(ss, off);
            const float rinv = __builtin_amdgcn_rcpf(ss);
            attn[t][lane]      = e0 * rinv;
            attn[t][64 + lane] = e1 * rinv;
        }
        __syncthreads();
    }

    // ---- Phase 2: context[ti][d] = sum_k attn[ti][k] * knw[b][k][d] ----
    // Wave w handles k in [32w, 32w+32); thread covers d4 = 4*lane.
    const int kg = wave;
    const int dq = lane;
    float a_reg[TT_];
#pragma unroll
    for (int ti = 0; ti < TT_; ti++)
        a_reg[ti] = attn[ti][kg * 32 + (lane & 31)];  // 1 LDS read, then shfl

    float4 acc[TT_];
#pragma unroll
    for (int ti = 0; ti < TT_; ti++) acc[ti] = make_float4(0.f, 0.f, 0.f, 0.f);

    const float* kp = &knw[(b * K_ + kg * 32) * DK_ + dq * 4];
#pragma unroll 4
    for (int ki = 0; ki < 32; ki++) {
        const float4 kn = *(const float4*)&kp[ki * DK_];  // wave reads 1KB row
#pragma unroll
        for (int ti = 0; ti < TT_; ti++) {
            const float a = __shfl(a_reg[ti], ki);        // broadcast via VALU
            acc[ti].x = fmaf(a, kn.x, acc[ti].x);
            acc[ti].y = fmaf(a, kn.y, acc[ti].y);
            acc[ti].z = fmaf(a, kn.z, acc[ti].z);
            acc[ti].w = fmaf(a, kn.w, acc[ti].w);
        }
    }
#pragma unroll
    for (int ti = 0; ti < TT_; ti++)
        *(float4*)&part2[kg][ti][dq * 4] = acc[ti];
    __syncthreads();

    // Cross-wave K reduction + coalesced float4 store
    for (int i = tid; i < 512; i += 256) {
        const int ti = i >> 6, dd = i & 63;
        const float4 s0 = *(const float4*)&part2[0][ti][dd * 4];
        const float4 s1 = *(const float4*)&part2[1][ti][dd * 4];
        const float4 s2 = *(const float4*)&part2[2][ti][dd * 4];
        const float4 s3 = *(const float4*)&part2[3][ti][dd * 4];
        float4 o;
        o.x = s0.x + s1.x + s2.x + s3.x;
        o.y = s0.y + s1.y + s2.y + s3.y;
        o.z = s0.z + s1.z + s2.z + s3.z;
        o.w = s0.w + s1.w + s2.w + s3.w;
        *(float4*)&out[(b * T_ + t0 + ti) * DK_ + dd * 4] = o;
    }
}

// ---------------------------------------------------------------------------
extern "C" void kernel_launch(void* const* d_in, const int* in_sizes, int n_in,
                              void* d_out, int out_size, void* d_ws,
                              size_t ws_size, hipStream_t stream) {
    (void)in_sizes; (void)n_in; (void)d_ws; (void)ws_size; (void)out_size;
    const float* knw = (const float*)d_in[0];  // [B,K,DK]
    const float* enc = (const float*)d_in[1];  // [B,T,DE]
    const float* W1  = (const float*)d_in[2];  // [DE,U]
    const float* b1  = (const float*)d_in[3];  // [U]
    const float* W2  = (const float*)d_in[4];  // [DK,U]
    const float* b2  = (const float*)d_in[5];  // [U]
    const float* V   = (const float*)d_in[6];  // [U,1]
    // d_in[7] = bV: constant shift over K, cancels in softmax -> unused.
    float* out = (float*)d_out;

    gemm2x<<<(B_ * T_) / 8, 256, 0, stream>>>(enc, W1, b1, 0);  // E2
    gemm2x<<<(B_ * K_) / 8, 256, 0, stream>>>(knw, W2, b2, 1);  // Km2
    attn_ctx<<<B_ * (T_ / TT_), 256, 0, stream>>>(knw, V, out);
}

// Round 2
// 110.229 us; speedup vs baseline: 1.1905x; 1.1905x over previous
//
#include <hip/hip_runtime.h>

// Problem constants
#define B_  16
#define T_  256
#define K_  128
#define DK_ 256
#define U_  128
#define TT_ 4      // timesteps per attn block (grid = 16*64 = 1024 -> 4 blocks/CU)

#define SCALE_ 2.8853900817779268f  // 2*log2(e): exp(2x) = exp2(SCALE_*x)

// Static device scratch. Both hold SCALE_*(X@W + b):
// g_E2[m][u],  m in [0, B*T);  g_Km2[n][u], n in [0, B*K)
__device__ float g_E2[B_ * T_ * U_];
__device__ float g_Km2[B_ * K_ * U_];

// ---------------------------------------------------------------------------
// Fused GEMMs: blocks [0,256) -> E (4096 rows of enc@W1+b1),
//              blocks [256,384) -> Km (2048 rows of knw@W2+b2).
// 16 rows/block, 2 rows/thread: 32 fma per 4 global float4 loads.
// ---------------------------------------------------------------------------
__global__ __launch_bounds__(256) void gemm_both(const float* __restrict__ enc,
                                                 const float* __restrict__ W1,
                                                 const float* __restrict__ b1,
                                                 const float* __restrict__ knw,
                                                 const float* __restrict__ W2,
                                                 const float* __restrict__ b2) {
    __shared__ float Xs[16][256];   // 16 KB

    const int blk  = blockIdx.x;
    const bool isE = blk < 256;
    const float* __restrict__ X    = isE ? enc : knw;
    const float* __restrict__ W    = isE ? W1 : W2;
    const float* __restrict__ bias = isE ? b1 : b2;
    float* __restrict__ Y          = isE ? g_E2 : g_Km2;
    const int row0 = (isE ? blk : blk - 256) * 16;
    const int tid  = threadIdx.x;

    // Stage 16 rows x 256 floats = 1024 float4, 4 per thread, coalesced.
#pragma unroll
    for (int j = 0; j < 4; j++) {
        const int i  = tid + j * 256;
        const int rr = i >> 6, cc = i & 63;
        *(float4*)&Xs[rr][cc * 4] =
            *(const float4*)&X[(row0 + rr) * 256 + cc * 4];
    }
    __syncthreads();

    const int uc = tid & 31;          // u4 = 4*uc
    const int rp = (tid >> 5) * 2;    // rows rp, rp+1
    float4 a0 = {0.f, 0.f, 0.f, 0.f};
    float4 a1 = {0.f, 0.f, 0.f, 0.f};

    for (int d = 0; d < 256; d += 4) {
        const float4 xa = *(const float4*)&Xs[rp][d];       // broadcast
        const float4 xb = *(const float4*)&Xs[rp + 1][d];   // broadcast
        const float* wp = &W[d * 128 + uc * 4];
        const float4 w0 = *(const float4*)(wp);
        const float4 w1 = *(const float4*)(wp + 128);
        const float4 w2 = *(const float4*)(wp + 256);
        const float4 w3 = *(const float4*)(wp + 384);
        a0.x = fmaf(xa.x, w0.x, a0.x); a0.y = fmaf(xa.x, w0.y, a0.y);
        a0.z = fmaf(xa.x, w0.z, a0.z); a0.w = fmaf(xa.x, w0.w, a0.w);
        a0.x = fmaf(xa.y, w1.x, a0.x); a0.y = fmaf(xa.y, w1.y, a0.y);
        a0.z = fmaf(xa.y, w1.z, a0.z); a0.w = fmaf(xa.y, w1.w, a0.w);
        a0.x = fmaf(xa.z, w2.x, a0.x); a0.y = fmaf(xa.z, w2.y, a0.y);
        a0.z = fmaf(xa.z, w2.z, a0.z); a0.w = fmaf(xa.z, w2.w, a0.w);
        a0.x = fmaf(xa.w, w3.x, a0.x); a0.y = fmaf(xa.w, w3.y, a0.y);
        a0.z = fmaf(xa.w, w3.z, a0.z); a0.w = fmaf(xa.w, w3.w, a0.w);
        a1.x = fmaf(xb.x, w0.x, a1.x); a1.y = fmaf(xb.x, w0.y, a1.y);
        a1.z = fmaf(xb.x, w0.z, a1.z); a1.w = fmaf(xb.x, w0.w, a1.w);
        a1.x = fmaf(xb.y, w1.x, a1.x); a1.y = fmaf(xb.y, w1.y, a1.y);
        a1.z = fmaf(xb.y, w1.z, a1.z); a1.w = fmaf(xb.y, w1.w, a1.w);
        a1.x = fmaf(xb.z, w2.x, a1.x); a1.y = fmaf(xb.z, w2.y, a1.y);
        a1.z = fmaf(xb.z, w2.z, a1.z); a1.w = fmaf(xb.z, w2.w, a1.w);
        a1.x = fmaf(xb.w, w3.x, a1.x); a1.y = fmaf(xb.w, w3.y, a1.y);
        a1.z = fmaf(xb.w, w3.z, a1.z); a1.w = fmaf(xb.w, w3.w, a1.w);
    }

    const float4 b4 = *(const float4*)&bias[uc * 4];
    float4 o0, o1;
    o0.x = SCALE_ * (a0.x + b4.x); o0.y = SCALE_ * (a0.y + b4.y);
    o0.z = SCALE_ * (a0.z + b4.z); o0.w = SCALE_ * (a0.w + b4.w);
    o1.x = SCALE_ * (a1.x + b4.x); o1.y = SCALE_ * (a1.y + b4.y);
    o1.z = SCALE_ * (a1.z + b4.z); o1.w = SCALE_ * (a1.w + b4.w);
    *(float4*)&Y[(row0 + rp) * 128 + uc * 4]     = o0;
    *(float4*)&Y[(row0 + rp + 1) * 128 + uc * 4] = o1;
}

// ---------------------------------------------------------------------------
// Fused scores -> softmax -> context. One block per (b, tile of 4 t's).
// score_k = const - sum_u 2V[u]/(1+exp2(E2[t,u]+Km2[k,u])); consts cancel
// in softmax over K. 4 barriers total; softmax parallel across 4 waves.
// ---------------------------------------------------------------------------
__global__ __launch_bounds__(256, 4) void attn_ctx(const float* __restrict__ knw,
                                                   const float* __restrict__ V,
                                                   float* __restrict__ out) {
    __shared__ float sm[4][TT_][256];   // 16 KB: phase1 pA/V2s, phase2 part2
    __shared__ float E2s[TT_][U_];      // 2 KB
    __shared__ float attn[TT_][K_];     // 2 KB
    float* const pA  = &sm[0][0][0];    // [TT_][256] score partials
    float* const V2s = &sm[1][0][0];    // 128 floats = 2*V

    const int tid  = threadIdx.x;
    const int blk  = blockIdx.x;
    const int b    = blk >> 6;          // 64 t-tiles per batch
    const int t0   = (blk & 63) * TT_;
    const int lane = tid & 63;
    const int wave = tid >> 6;

    if (tid < 128) V2s[tid] = 2.0f * V[tid];
    if (tid < 128) {                    // stage E2 rows (4 x 128)
        const int ti = tid >> 5, uc = tid & 31;
        *(float4*)&E2s[ti][uc * 4] =
            *(const float4*)&g_E2[(b * T_ + t0 + ti) * U_ + uc * 4];
    }

    // Thread owns (k, half-of-U): 64 Km2 values in VGPRs, reused over 4 t's.
    const int k_idx = tid & 127;
    const int half  = tid >> 7;
    float4 km[16];
    {
        const float* kp = &g_Km2[(b * K_ + k_idx) * U_ + half * 64];
#pragma unroll
        for (int c = 0; c < 16; c++) km[c] = *(const float4*)&kp[c * 4];
    }
    __syncthreads();

    // ---- Phase 1: negacc[t] = sum_{u in half} 2V[u]/(1+exp2(e'+k')) ----
    {
        float na[TT_] = {0.f, 0.f, 0.f, 0.f};
#pragma unroll
        for (int c = 0; c < 16; c++) {
            const float4 v4 = *(const float4*)&V2s[half * 64 + c * 4];
#pragma unroll
            for (int t = 0; t < TT_; t++) {
                const float4 e4 = *(const float4*)&E2s[t][half * 64 + c * 4];
                float x, r;
                x = e4.x + km[c].x;
                r = __builtin_amdgcn_rcpf(1.0f + __builtin_amdgcn_exp2f(x));
                na[t] = fmaf(v4.x, r, na[t]);
                x = e4.y + km[c].y;
                r = __builtin_amdgcn_rcpf(1.0f + __builtin_amdgcn_exp2f(x));
                na[t] = fmaf(v4.y, r, na[t]);
                x = e4.z + km[c].z;
                r = __builtin_amdgcn_rcpf(1.0f + __builtin_amdgcn_exp2f(x));
                na[t] = fmaf(v4.z, r, na[t]);
                x = e4.w + km[c].w;
                r = __builtin_amdgcn_rcpf(1.0f + __builtin_amdgcn_exp2f(x));
                na[t] = fmaf(v4.w, r, na[t]);
            }
        }
#pragma unroll
        for (int t = 0; t < TT_; t++) pA[t * 256 + tid] = na[t];
    }
    __syncthreads();

    // ---- Softmax over K=128: wave w owns timestep w ----
    {
        const int t = wave;
        const float* p = &pA[t * 256];
        float s0 = -(p[lane] + p[128 + lane]);
        float s1 = -(p[64 + lane] + p[192 + lane]);
        float m = fmaxf(s0, s1);
#pragma unroll
        for (int off = 32; off >= 1; off >>= 1)
            m = fmaxf(m, __shfl_xor(m, off));
        const float e0 = __builtin_amdgcn_exp2f(1.4426950408889634f * (s0 - m));
        const float e1 = __builtin_amdgcn_exp2f(1.4426950408889634f * (s1 - m));
        float ss = e0 + e1;
#pragma unroll
        for (int off = 32; off >= 1; off >>= 1)
            ss += __shfl_xor(ss, off);
        const float rinv = __builtin_amdgcn_rcpf(ss);
        attn[t][lane]      = e0 * rinv;
        attn[t][64 + lane] = e1 * rinv;
    }
    __syncthreads();

    // ---- Phase 2: context[ti][d] = sum_k attn[ti][k]*knw[b][k][d] ----
    // Wave kg covers k in [32kg, 32kg+32); lane covers d4 = 4*lane.
    {
        const int kg = wave, dq = lane;
        float4 acc[TT_];
#pragma unroll
        for (int ti = 0; ti < TT_; ti++) acc[ti] = make_float4(0.f, 0.f, 0.f, 0.f);

        const float* kp = &knw[(b * K_ + kg * 32) * DK_ + dq * 4];
#pragma unroll 4
        for (int ki = 0; ki < 32; ki++) {
            const float4 kn = *(const float4*)&kp[ki * DK_];
#pragma unroll
            for (int ti = 0; ti < TT_; ti++) {
                const float a = attn[ti][kg * 32 + ki];   // LDS broadcast
                acc[ti].x = fmaf(a, kn.x, acc[ti].x);
                acc[ti].y = fmaf(a, kn.y, acc[ti].y);
                acc[ti].z = fmaf(a, kn.z, acc[ti].z);
                acc[ti].w = fmaf(a, kn.w, acc[ti].w);
            }
        }
#pragma unroll
        for (int ti = 0; ti < TT_; ti++)
            *(float4*)&sm[kg][ti][dq * 4] = acc[ti];
    }
    __syncthreads();

    // Cross-wave K reduction + coalesced float4 store (4 rows x 256)
    {
        const int ti = tid >> 6, dd = tid & 63;
        const float4 s0 = *(const float4*)&sm[0][ti][dd * 4];
        const float4 s1 = *(const float4*)&sm[1][ti][dd * 4];
        const float4 s2 = *(const float4*)&sm[2][ti][dd * 4];
        const float4 s3 = *(const float4*)&sm[3][ti][dd * 4];
        float4 o;
        o.x = s0.x + s1.x + s2.x + s3.x;
        o.y = s0.y + s1.y + s2.y + s3.y;
        o.z = s0.z + s1.z + s2.z + s3.z;
        o.w = s0.w + s1.w + s2.w + s3.w;
        *(float4*)&out[(b * T_ + t0 + ti) * DK_ + dd * 4] = o;
    }
}

// ---------------------------------------------------------------------------
extern "C" void kernel_launch(void* const* d_in, const int* in_sizes, int n_in,
                              void* d_out, int out_size, void* d_ws,
                              size_t ws_size, hipStream_t stream) {
    (void)in_sizes; (void)n_in; (void)d_ws; (void)ws_size; (void)out_size;
    const float* knw = (const float*)d_in[0];  // [B,K,DK]
    const float* enc = (const float*)d_in[1];  // [B,T,DE]
    const float* W1  = (const float*)d_in[2];  // [DE,U]
    const float* b1  = (const float*)d_in[3];  // [U]
    const float* W2  = (const float*)d_in[4];  // [DK,U]
    const float* b2  = (const float*)d_in[5];  // [U]
    const float* V   = (const float*)d_in[6];  // [U,1]
    // d_in[7] = bV: constant over K, cancels in softmax -> unused.
    float* out = (float*)d_out;

    gemm_both<<<384, 256, 0, stream>>>(enc, W1, b1, knw, W2, b2);
    attn_ctx<<<B_ * (T_ / TT_), 256, 0, stream>>>(knw, V, out);
}